// Round 2
// 423.895 us; speedup vs baseline: 1.0556x; 1.0556x over previous
//
#include <hip/hip_runtime.h>

// Controlled 2-qubit gate on a 26-qubit float32 state vector.
// Flat element-index bits: q0 = bit 25, q1 = bit 24, control q2 = bit 23,
// r = bits 0..22.  In float4-index space (element>>2) these are bits 23, 22, 21.
//
// Grid is split into two regions:
//   blocks [0, 8192):      gate half  (q2 = 1)  -- 4-quadrant gather + 4x4 matmul
//   blocks [8192, 16384):  copy half  (q2 = 0)  -- pure linear memcpy
//
// Gate half: out[t] = sum_s M[t][s] * a[s], s ordered (base, +q1, +q0, +q0+q1),
// matching row-major 4x4 `mat` with t = 2*q0 + q1.

typedef float f4 __attribute__((ext_vector_type(4)));   // native vector: nontemporal-ok

constexpr unsigned kGateBlocks = 8192u;   // 2^21 float4 per quadrant / 256 threads
constexpr unsigned kQ2f4  = 1u << 21;     // q2 bit in float4-index space
constexpr unsigned kQ1f4  = 1u << 22;     // q1 bit in float4-index space
constexpr unsigned kQ0f4  = 1u << 23;     // q0 bit in float4-index space

__global__ __launch_bounds__(256) void gate_kernel(const f4* __restrict__ x4,
                                                   const float* __restrict__ mat,
                                                   f4* __restrict__ o4) {
    const unsigned bid = blockIdx.x;

    if (bid < kGateBlocks) {
        // ---- gate half: q2 = 1 ----
        const unsigned g  = bid * 256u + threadIdx.x;   // [0, 2^21)
        const unsigned i0 = kQ2f4 | g;                  // (q0,q1) = (0,0)
        const unsigned i1 = i0 + kQ1f4;                 // (0,1)
        const unsigned i2 = i0 + kQ0f4;                 // (1,0)
        const unsigned i3 = i0 + kQ0f4 + kQ1f4;         // (1,1)

        const f4 a0 = __builtin_nontemporal_load(&x4[i0]);
        const f4 a1 = __builtin_nontemporal_load(&x4[i1]);
        const f4 a2 = __builtin_nontemporal_load(&x4[i2]);
        const f4 a3 = __builtin_nontemporal_load(&x4[i3]);

        float m[16];
#pragma unroll
        for (int k = 0; k < 16; ++k) m[k] = mat[k];     // wave-uniform -> s_load

        f4 b0, b1, b2, b3;
#pragma unroll
        for (int c = 0; c < 4; ++c) {
            b0[c] = m[0]*a0[c]  + m[1]*a1[c]  + m[2]*a2[c]  + m[3]*a3[c];
            b1[c] = m[4]*a0[c]  + m[5]*a1[c]  + m[6]*a2[c]  + m[7]*a3[c];
            b2[c] = m[8]*a0[c]  + m[9]*a1[c]  + m[10]*a2[c] + m[11]*a3[c];
            b3[c] = m[12]*a0[c] + m[13]*a1[c] + m[14]*a2[c] + m[15]*a3[c];
        }

        __builtin_nontemporal_store(b0, &o4[i0]);
        __builtin_nontemporal_store(b1, &o4[i1]);
        __builtin_nontemporal_store(b2, &o4[i2]);
        __builtin_nontemporal_store(b3, &o4[i3]);
    } else {
        // ---- copy half: q2 = 0 ----
        // t enumerates the 2^23 float4s of the q2=0 half; re-insert bit21=0.
        const unsigned cb   = bid - kGateBlocks;
        const unsigned base = cb * 1024u + threadIdx.x;
#pragma unroll
        for (int k = 0; k < 4; ++k) {
            const unsigned t = base + k * 256u;                       // [0, 2^23)
            const unsigned s = ((t >> 21) << 22) | (t & 0x1FFFFFu);   // q2=0 slot
            __builtin_nontemporal_store(__builtin_nontemporal_load(&x4[s]), &o4[s]);
        }
    }
}

extern "C" void kernel_launch(void* const* d_in, const int* in_sizes, int n_in,
                              void* d_out, int out_size, void* d_ws, size_t ws_size,
                              hipStream_t stream) {
    const f4* x4  = (const f4*)d_in[0];     // 2^26 floats
    const float* mat = (const float*)d_in[1];  // 16 floats, row-major 4x4
    f4* o4 = (f4*)d_out;                    // 2^26 floats

    const unsigned grid  = 16384;   // 8192 gate blocks + 8192 copy blocks
    const unsigned block = 256;
    gate_kernel<<<grid, block, 0, stream>>>(x4, mat, o4);
}

// Round 3
// 421.460 us; speedup vs baseline: 1.0617x; 1.0058x over previous
//
#include <hip/hip_runtime.h>

// Controlled 2-qubit gate on a 26-qubit float32 state vector.
// Flat element-index bits: q0 = bit 25, q1 = bit 24, control q2 = bit 23,
// r = bits 0..22.  In float4-index space (element>>2) these are bits 23, 22, 21.
//
// Grid split:
//   blocks [0, 4096):      gate half (q2=1), 2 float4 per thread per quadrant
//   blocks [4096, 8192):   copy half (q2=0), 8 float4 per thread, batched
//
// Gate: out[t] = sum_s M[t][s] * a[s], s ordered (base, +q1, +q0, +q0+q1),
// row-major 4x4 `mat`, t = 2*q0 + q1.

typedef float f4 __attribute__((ext_vector_type(4)));   // native vector: nontemporal-ok

constexpr unsigned kGateBlocks = 4096u;   // 2^21 f4 per quadrant / (256 thr * 2 f4)
constexpr unsigned kQ2f4  = 1u << 21;     // q2 bit in float4-index space
constexpr unsigned kQ1f4  = 1u << 22;     // q1 bit in float4-index space
constexpr unsigned kQ0f4  = 1u << 23;     // q0 bit in float4-index space

__global__ __launch_bounds__(256) void gate_kernel(const f4* __restrict__ x4,
                                                   const float* __restrict__ mat,
                                                   f4* __restrict__ o4) {
    const unsigned bid = blockIdx.x;

    if (bid < kGateBlocks) {
        // ---- gate half: q2 = 1; 2 consecutive-coalesced f4 per thread ----
        const unsigned g0 = bid * 512u + threadIdx.x;       // [0, 2^21), lane-unit-stride
        unsigned idx[2][4];
#pragma unroll
        for (int j = 0; j < 2; ++j) {
            const unsigned g  = g0 + j * 256u;
            idx[j][0] = kQ2f4 | g;                  // (q0,q1) = (0,0)
            idx[j][1] = idx[j][0] + kQ1f4;          // (0,1)
            idx[j][2] = idx[j][0] + kQ0f4;          // (1,0)
            idx[j][3] = idx[j][0] + kQ0f4 + kQ1f4;  // (1,1)
        }

        // issue all 8 loads before any dependent use (8 outstanding dwordx4)
        f4 a[2][4];
#pragma unroll
        for (int j = 0; j < 2; ++j)
#pragma unroll
            for (int s = 0; s < 4; ++s)
                a[j][s] = __builtin_nontemporal_load(&x4[idx[j][s]]);

        float m[16];
#pragma unroll
        for (int k = 0; k < 16; ++k) m[k] = mat[k];     // wave-uniform -> s_load

        f4 b[2][4];
#pragma unroll
        for (int j = 0; j < 2; ++j)
#pragma unroll
            for (int c = 0; c < 4; ++c) {
                b[j][0][c] = m[0]*a[j][0][c]  + m[1]*a[j][1][c]  + m[2]*a[j][2][c]  + m[3]*a[j][3][c];
                b[j][1][c] = m[4]*a[j][0][c]  + m[5]*a[j][1][c]  + m[6]*a[j][2][c]  + m[7]*a[j][3][c];
                b[j][2][c] = m[8]*a[j][0][c]  + m[9]*a[j][1][c]  + m[10]*a[j][2][c] + m[11]*a[j][3][c];
                b[j][3][c] = m[12]*a[j][0][c] + m[13]*a[j][1][c] + m[14]*a[j][2][c] + m[15]*a[j][3][c];
            }

#pragma unroll
        for (int j = 0; j < 2; ++j)
#pragma unroll
            for (int s = 0; s < 4; ++s)
                __builtin_nontemporal_store(b[j][s], &o4[idx[j][s]]);
    } else {
        // ---- copy half: q2 = 0; 8 f4 per thread, all loads then all stores ----
        const unsigned cb   = bid - kGateBlocks;
        const unsigned base = cb * 2048u + threadIdx.x;     // t-space [0, 2^23)
        unsigned s[8];
        f4 v[8];
#pragma unroll
        for (int k = 0; k < 8; ++k) {
            const unsigned t = base + k * 256u;
            s[k] = ((t >> 21) << 22) | (t & 0x1FFFFFu);     // re-insert q2=0 bit
        }
#pragma unroll
        for (int k = 0; k < 8; ++k) v[k] = __builtin_nontemporal_load(&x4[s[k]]);
#pragma unroll
        for (int k = 0; k < 8; ++k) __builtin_nontemporal_store(v[k], &o4[s[k]]);
    }
}

extern "C" void kernel_launch(void* const* d_in, const int* in_sizes, int n_in,
                              void* d_out, int out_size, void* d_ws, size_t ws_size,
                              hipStream_t stream) {
    const f4* x4  = (const f4*)d_in[0];        // 2^26 floats
    const float* mat = (const float*)d_in[1];  // 16 floats, row-major 4x4
    f4* o4 = (f4*)d_out;                       // 2^26 floats

    const unsigned grid  = 8192;    // 4096 gate blocks + 4096 copy blocks
    const unsigned block = 256;
    gate_kernel<<<grid, block, 0, stream>>>(x4, mat, o4);
}